// Round 19
// baseline (273.822 us; speedup 1.0000x reference)
//
#include <hip/hip_runtime.h>

#define EMB_D 64
#define CSHIFT 9    // class = row >> 9 (512 rows/class)
#define CROWS  (1 << CSHIFT)
#define CMASK  (CROWS - 1)
#define MAXC 384    // max classes (M <= 196608; col fits 18 bits)
#define SFLAG (1 << 27)
#define EPB 4096    // edges per bin/count block (16 per thread)

typedef float    float4v __attribute__((ext_vector_type(4)));
typedef float    float8v __attribute__((ext_vector_type(8)));
typedef _Float16 half4v  __attribute__((ext_vector_type(4)));
typedef _Float16 half8v  __attribute__((ext_vector_type(8)));

__device__ inline float8v tof32x8(half8v v) { return __builtin_convertvector(v, float8v); }

// ---------------------------------------------------------------------------
// class_cnt: per-block per-class entry counts. EPB edges/block, LDS
// histogram -> DENSE row store percls[blk][c] (no global atomics at all).
// ---------------------------------------------------------------------------
__global__ void __launch_bounds__(256) class_cnt(const int* __restrict__ eu,
                                                 const int* __restrict__ ei,
                                                 int E, int nbE,
                                                 const int* __restrict__ sr, int S,
                                                 int U, int* __restrict__ percls) {
    __shared__ int hist[MAXC];
    for (int t = threadIdx.x; t < MAXC; t += 256) hist[t] = 0;
    __syncthreads();
    int blk = blockIdx.x;
    if (blk < nbE) {
        int e0 = blk * EPB, e1 = min(e0 + EPB, E);
        for (int e = e0 + threadIdx.x; e < e1; e += 256) {
            atomicAdd(&hist[eu[e] >> CSHIFT], 1);
            atomicAdd(&hist[(U + ei[e]) >> CSHIFT], 1);
        }
    } else {
        int e0 = (blk - nbE) * EPB, e1 = min(e0 + EPB, S);
        for (int e = e0 + threadIdx.x; e < e1; e += 256) {
            atomicAdd(&hist[(U + sr[e]) >> CSHIFT], 1);
        }
    }
    __syncthreads();
    for (int t = threadIdx.x; t < MAXC; t += 256)
        percls[(long)blk * MAXC + t] = hist[t];
}

// ---------------------------------------------------------------------------
// colscan: one block per class c. Exclusive scan over blocks of
// percls[blk][c] -> per-block chunk base offsets; total -> ctot[c].
// ---------------------------------------------------------------------------
__global__ void __launch_bounds__(512) colscan(int* __restrict__ percls, int NB,
                                               int* __restrict__ ctot) {
    __shared__ int sh[512];
    int c = blockIdx.x;
    int t = threadIdx.x;
    int v = (t < NB) ? percls[(long)t * MAXC + c] : 0;
    sh[t] = v;
    __syncthreads();
    for (int ofs = 1; ofs < 512; ofs <<= 1) {
        int x = (t >= ofs) ? sh[t - ofs] : 0;
        __syncthreads();
        sh[t] += x;
        __syncthreads();
    }
    if (t < NB) percls[(long)t * MAXC + c] = sh[t] - v;  // exclusive
    if (t == 511) ctot[c] = sh[511];
}

// ---------------------------------------------------------------------------
// class_scan: 1-block exclusive scan over NC class totals -> bkptr.
// ---------------------------------------------------------------------------
__global__ void __launch_bounds__(512) class_scan(const int* __restrict__ ctot, int NC,
                                                  int* __restrict__ bkptr) {
    __shared__ int sh[512];
    int t = threadIdx.x;
    int v = (t < NC) ? ctot[t] : 0;
    sh[t] = v;
    __syncthreads();
    for (int ofs = 1; ofs < 512; ofs <<= 1) {
        int x = (t >= ofs) ? sh[t - ofs] : 0;
        __syncthreads();
        sh[t] += x;
        __syncthreads();
    }
    if (t < NC) bkptr[t] = sh[t] - v;
    if (t == 511) bkptr[NC] = sh[511];
}

// ---------------------------------------------------------------------------
// bin: single-pass append into per-class buckets. Chunk base comes from
// bkptr[c] + percls[blk][c] (precomputed, no global atomics); intra-chunk
// offset via LDS hist. ~28-entry contiguous chunks -> ~1.3x write amp.
// Entry .x = (sflag<<27) | (row_lo<<18) | col ; .y = sv bits (s) or 0 (bip).
// ---------------------------------------------------------------------------
__global__ void __launch_bounds__(256) bin_kernel(const int* __restrict__ eu,
                                                  const int* __restrict__ ei,
                                                  int E, int nbE,
                                                  const int* __restrict__ sr,
                                                  const int* __restrict__ sc,
                                                  const float* __restrict__ sv, int S,
                                                  int U,
                                                  const int* __restrict__ bkptr,
                                                  const int* __restrict__ percls,
                                                  int2* __restrict__ bent) {
    __shared__ int hist[MAXC];
    __shared__ int base[MAXC];
    int blk = blockIdx.x;
    for (int t = threadIdx.x; t < MAXC; t += 256) {
        base[t] = bkptr[t] + percls[(long)blk * MAXC + t];
        hist[t] = 0;
    }
    __syncthreads();

    if (blk < nbE) {
        int e0 = blk * EPB, e1 = min(e0 + EPB, E);
        for (int e = e0 + threadIdx.x; e < e1; e += 256) {
            int u  = eu[e];
            int iv = U + ei[e];
            int c0 = u >> CSHIFT, c1 = iv >> CSHIFT;
            int o0 = atomicAdd(&hist[c0], 1);
            bent[base[c0] + o0] = make_int2(((u & CMASK) << 18) | iv, 0);
            int o1 = atomicAdd(&hist[c1], 1);
            bent[base[c1] + o1] = make_int2(((iv & CMASK) << 18) | u, 0);
        }
    } else {
        int e0 = (blk - nbE) * EPB, e1 = min(e0 + EPB, S);
        for (int e = e0 + threadIdx.x; e < e1; e += 256) {
            int dst = U + sr[e];
            int c = dst >> CSHIFT;
            int o = atomicAdd(&hist[c], 1);
            bent[base[c] + o] = make_int2(SFLAG | ((dst & CMASK) << 18) | (U + sc[e]),
                                          __float_as_int(sv[e]));
        }
    }
}

// ---------------------------------------------------------------------------
// cls_hist (pass A): one 1024-thread block per 512-row class. Streams its
// bucket: LDS histograms (bip-degree + total per row) -> norm =
// rsqrt(bipdeg+1), LDS scan -> rowptr. No global row atomics anywhere.
// ---------------------------------------------------------------------------
__global__ void __launch_bounds__(1024) cls_hist(const int* __restrict__ bkptr,
                                                 const int2* __restrict__ bent,
                                                 float* __restrict__ norm,
                                                 int* __restrict__ rowptr, int M) {
    __shared__ int cntb[CROWS];
    __shared__ int cntt[CROWS];
    int c   = blockIdx.x;
    int rlo = c << CSHIFT;
    int nrows = min(CROWS, M - rlo);
    if (threadIdx.x < CROWS) {
        cntb[threadIdx.x] = 0;
        cntt[threadIdx.x] = 0;
    }
    __syncthreads();

    int beg = bkptr[c], end = bkptr[c + 1];
    for (int k = beg + threadIdx.x; k < end; k += 1024) {
        int x = bent[k].x;
        int rl = (x >> 18) & CMASK;
        atomicAdd(&cntt[rl], 1);
        if (!(x & SFLAG)) atomicAdd(&cntb[rl], 1);
    }
    __syncthreads();

    int my = 0;
    if (threadIdx.x < CROWS) {
        my = cntt[threadIdx.x];
        if (threadIdx.x < nrows)
            norm[rlo + threadIdx.x] = rsqrtf((float)cntb[threadIdx.x] + 1.0f);
    }
    for (int ofs = 1; ofs < CROWS; ofs <<= 1) {
        int x = (threadIdx.x >= ofs && threadIdx.x < CROWS) ? cntt[threadIdx.x - ofs] : 0;
        __syncthreads();
        if (threadIdx.x < CROWS) cntt[threadIdx.x] += x;
        __syncthreads();
    }
    if (threadIdx.x < CROWS && threadIdx.x < nrows)
        rowptr[rlo + threadIdx.x] = beg + cntt[threadIdx.x] - my;   // exclusive
    if (threadIdx.x == 0) rowptr[rlo + nrows] = end;  // covers rowptr[M]
}

// ---------------------------------------------------------------------------
// cls_scatter (pass B): one 1024-thread block per class. Row cursors AND
// own-class norms in LDS; re-streams the bucket (L2-hot from pass A) and
// writes final (col, w) entries into the exclusively-owned CSR window
// (single XCD, temporally dense -> ~1x write amp). Bip weight computed as
// norm[row]*norm[col] (same operand order as fill_w -> bit-identical).
// ---------------------------------------------------------------------------
__global__ void __launch_bounds__(1024) cls_scatter(const int* __restrict__ bkptr,
                                                    const int2* __restrict__ bent,
                                                    const float* __restrict__ norm,
                                                    const int* __restrict__ rowptr,
                                                    int2* __restrict__ ent, int M) {
    __shared__ int   cur[CROWS];
    __shared__ float nloc[CROWS];
    int c   = blockIdx.x;
    int rlo = c << CSHIFT;
    int nrows = min(CROWS, M - rlo);
    if (threadIdx.x < CROWS) {
        int r = (threadIdx.x < nrows) ? rlo + threadIdx.x : rlo;
        cur[threadIdx.x]  = rowptr[r];
        nloc[threadIdx.x] = norm[r];
    }
    __syncthreads();

    int beg = bkptr[c], end = bkptr[c + 1];
    for (int k = beg + threadIdx.x; k < end; k += 1024) {
        int2 e = bent[k];
        int rl  = (e.x >> 18) & CMASK;
        int col = e.x & 0x3FFFF;
        int p = atomicAdd(&cur[rl], 1);
        float w = (e.x & SFLAG) ? __int_as_float(e.y) : nloc[rl] * norm[col];
        ent[p] = make_int2(col, __float_as_int(w));
    }
}

// ---------------------------------------------------------------------------
// cur0 (fp16) = concat(user_emb, item_emb)
// ---------------------------------------------------------------------------
__global__ void init_kernel(const float4v* __restrict__ ue, const float4v* __restrict__ ie,
                            long u4, long total4, half4v* __restrict__ curH) {
    long stride = (long)gridDim.x * blockDim.x;
    for (long idx = (long)blockIdx.x * blockDim.x + threadIdx.x; idx < total4; idx += stride) {
        float4v v = (idx < u4) ? ue[idx] : ie[idx - u4];
        curH[idx] = __builtin_convertvector(v, half4v);
    }
}

// ---------------------------------------------------------------------------
// gather: ONE 8-lane group per destination row (8 rows per wave), half8
// 16 B loads, 8-deep masked software pipeline -> 64 outstanding row loads
// per wave (~60 VGPR, still 8 waves/SIMD). Heavy-first: item rows first.
// MODE 0: curH -> dstH (pure propagate, fp16)
// MODE 2: curH=e2 random-read -> out = 0.25*(e0+e1+e2+acc) from sequential
//         fp16 own-row reads (deferred sum: no fp32 out partial round-trip)
// ---------------------------------------------------------------------------
template <int MODE>
__global__ void __launch_bounds__(256) gather_kernel(const int* __restrict__ rowptr,
                                                     const int2* __restrict__ ent,
                                                     const _Float16* __restrict__ curH,
                                                     const _Float16* __restrict__ cur0H,
                                                     const _Float16* __restrict__ cur1H,
                                                     _Float16* __restrict__ dstH,
                                                     float* __restrict__ out,
                                                     int U, int I, int M) {
    int raw = (int)((((long)blockIdx.x * blockDim.x) + threadIdx.x) >> 3);
    int l   = threadIdx.x & 7;
    if (raw >= M) return;
    int row = (raw < I) ? (U + raw) : (raw - I);   // heavy-first: items first
    int beg = rowptr[row];
    int end = rowptr[row + 1];
    const half8v* curv = (const half8v*)(const void*)curH;

    float8v acc = {0.f, 0.f, 0.f, 0.f, 0.f, 0.f, 0.f, 0.f};
    int j = beg;
    int2 a0 = (j + 0 < end) ? ent[j + 0] : make_int2(0, 0);
    int2 a1 = (j + 1 < end) ? ent[j + 1] : make_int2(0, 0);
    int2 a2 = (j + 2 < end) ? ent[j + 2] : make_int2(0, 0);
    int2 a3 = (j + 3 < end) ? ent[j + 3] : make_int2(0, 0);
    int2 a4 = (j + 4 < end) ? ent[j + 4] : make_int2(0, 0);
    int2 a5 = (j + 5 < end) ? ent[j + 5] : make_int2(0, 0);
    int2 a6 = (j + 6 < end) ? ent[j + 6] : make_int2(0, 0);
    int2 a7 = (j + 7 < end) ? ent[j + 7] : make_int2(0, 0);
    half8v v0 = curv[(long)a0.x * 8 + l];
    half8v v1 = curv[(long)a1.x * 8 + l];
    half8v v2 = curv[(long)a2.x * 8 + l];
    half8v v3 = curv[(long)a3.x * 8 + l];
    half8v v4 = curv[(long)a4.x * 8 + l];
    half8v v5 = curv[(long)a5.x * 8 + l];
    half8v v6 = curv[(long)a6.x * 8 + l];
    half8v v7 = curv[(long)a7.x * 8 + l];
    while (j + 8 < end) {
        int jn = j + 8;
        int2 b0 = (jn + 0 < end) ? ent[jn + 0] : make_int2(0, 0);
        int2 b1 = (jn + 1 < end) ? ent[jn + 1] : make_int2(0, 0);
        int2 b2 = (jn + 2 < end) ? ent[jn + 2] : make_int2(0, 0);
        int2 b3 = (jn + 3 < end) ? ent[jn + 3] : make_int2(0, 0);
        int2 b4 = (jn + 4 < end) ? ent[jn + 4] : make_int2(0, 0);
        int2 b5 = (jn + 5 < end) ? ent[jn + 5] : make_int2(0, 0);
        int2 b6 = (jn + 6 < end) ? ent[jn + 6] : make_int2(0, 0);
        int2 b7 = (jn + 7 < end) ? ent[jn + 7] : make_int2(0, 0);
        half8v u0 = curv[(long)b0.x * 8 + l];
        half8v u1 = curv[(long)b1.x * 8 + l];
        half8v u2 = curv[(long)b2.x * 8 + l];
        half8v u3 = curv[(long)b3.x * 8 + l];
        half8v u4 = curv[(long)b4.x * 8 + l];
        half8v u5 = curv[(long)b5.x * 8 + l];
        half8v u6 = curv[(long)b6.x * 8 + l];
        half8v u7 = curv[(long)b7.x * 8 + l];
        acc += __int_as_float(a0.y) * tof32x8(v0);
        acc += __int_as_float(a1.y) * tof32x8(v1);
        acc += __int_as_float(a2.y) * tof32x8(v2);
        acc += __int_as_float(a3.y) * tof32x8(v3);
        acc += __int_as_float(a4.y) * tof32x8(v4);
        acc += __int_as_float(a5.y) * tof32x8(v5);
        acc += __int_as_float(a6.y) * tof32x8(v6);
        acc += __int_as_float(a7.y) * tof32x8(v7);
        a0 = b0; a1 = b1; a2 = b2; a3 = b3;
        a4 = b4; a5 = b5; a6 = b6; a7 = b7;
        v0 = u0; v1 = u1; v2 = u2; v3 = u3;
        v4 = u4; v5 = u5; v6 = u6; v7 = u7;
        j = jn;
    }
    acc += __int_as_float(a0.y) * tof32x8(v0);
    acc += __int_as_float(a1.y) * tof32x8(v1);
    acc += __int_as_float(a2.y) * tof32x8(v2);
    acc += __int_as_float(a3.y) * tof32x8(v3);
    acc += __int_as_float(a4.y) * tof32x8(v4);
    acc += __int_as_float(a5.y) * tof32x8(v5);
    acc += __int_as_float(a6.y) * tof32x8(v6);
    acc += __int_as_float(a7.y) * tof32x8(v7);

    long o8 = (long)row * 8 + l;
    if (MODE == 0) {
        ((half8v*)dstH)[o8] = __builtin_convertvector(acc, half8v);
    } else {
        float8v e0 = tof32x8(((const half8v*)cur0H)[o8]);
        float8v e1 = tof32x8(((const half8v*)cur1H)[o8]);
        float8v e2 = tof32x8(curv[o8]);
        ((float8v*)out)[o8] = 0.25f * (e0 + e1 + e2 + acc);
    }
}

extern "C" void kernel_launch(void* const* d_in, const int* in_sizes, int n_in,
                              void* d_out, int out_size, void* d_ws, size_t ws_size,
                              hipStream_t stream) {
    const float* user_emb = (const float*)d_in[0];
    const float* item_emb = (const float*)d_in[1];
    const int*   edge_user = (const int*)d_in[2];
    const int*   edge_item = (const int*)d_in[3];
    const int*   s_row = (const int*)d_in[4];
    const int*   s_col = (const int*)d_in[5];
    const float* s_val = (const float*)d_in[6];
    float* out = (float*)d_out;

    const int U = in_sizes[0] / EMB_D;
    const int I = in_sizes[1] / EMB_D;
    const int M = U + I;
    const int E = in_sizes[2];
    const int S = in_sizes[4];
    const long MD = (long)M * EMB_D;
    const long NT = 2L * E + S;             // merged CSR entries
    const int NC = (M + CMASK) >> CSHIFT;   // number of row classes

    const int nbE2 = (E + EPB - 1) / EPB;
    const int nbS2 = (S + EPB - 1) / EPB;
    const int NB = nbE2 + nbS2;             // <= 512 for these sizes

    // workspace carve-up, 16B-aligned chunks
    char* p = (char*)d_ws;
    auto carve = [&](long bytes) {
        char* q = p;
        p += (bytes + 15) & ~15L;
        return q;
    };
    _Float16* cur0H = (_Float16*)carve(MD * sizeof(_Float16));  // e0 (fp16)
    _Float16* cur1H = (_Float16*)carve(MD * sizeof(_Float16));  // e1 (fp16)
    // cur2H (e2, fp16) aliases the bucket array: bucket dead before e2 written
    long aliasBytes = MD * (long)sizeof(_Float16) > (NT + 8) * (long)sizeof(int2)
                        ? MD * (long)sizeof(_Float16) : (NT + 8) * (long)sizeof(int2);
    char* aliasRgn = carve(aliasBytes);
    _Float16* cur2H = (_Float16*)aliasRgn;
    int2*     bent  = (int2*)aliasRgn;
    float* norm   = (float*)carve((long)M * sizeof(float));
    int*   rowptr = (int*)carve((long)(M + 1) * sizeof(int));
    int*   percls = (int*)carve((long)NB * MAXC * sizeof(int));
    int*   ctot   = (int*)carve((long)MAXC * sizeof(int));
    int*   bkptr  = (int*)carve((long)(MAXC + 1) * sizeof(int));
    int2*  ent    = (int2*)carve((NT + 8) * sizeof(int2));

    // 1) per-block per-class counts (dense stores, zero global atomics)
    class_cnt<<<NB, 256, 0, stream>>>(edge_user, edge_item, E, nbE2,
                                      s_row, S, U, percls);

    // 2) column scan over blocks -> chunk bases; class scan -> bkptr
    colscan<<<NC, 512, 0, stream>>>(percls, NB, ctot);
    class_scan<<<1, 512, 0, stream>>>(ctot, NC, bkptr);

    // 3) single-pass bin into class buckets (precomputed chunk bases)
    bin_kernel<<<NB, 256, 0, stream>>>(edge_user, edge_item, E, nbE2,
                                       s_row, s_col, s_val, S,
                                       U, bkptr, percls, bent);

    // 4a) pass A: per-class histograms -> norm + rowptr
    cls_hist<<<NC, 1024, 0, stream>>>(bkptr, bent, norm, rowptr, M);

    // 4b) pass B: scatter with in-flight weight computation
    cls_scatter<<<NC, 1024, 0, stream>>>(bkptr, bent, norm, rowptr, ent, M);

    // 5) init cur0 (fp16)
    init_kernel<<<2048, 256, 0, stream>>>((const float4v*)user_emb, (const float4v*)item_emb,
                                          (long)U * (EMB_D / 4), MD / 4, (half4v*)cur0H);

    // 6) L=3 gather layers: two pure propagates + deferred final sum
    const int gblocks = (int)(((long)M * 8 + 255) / 256);
    gather_kernel<0><<<gblocks, 256, 0, stream>>>(rowptr, ent, cur0H, nullptr, nullptr,
                                                  cur1H, nullptr, U, I, M);
    gather_kernel<0><<<gblocks, 256, 0, stream>>>(rowptr, ent, cur1H, nullptr, nullptr,
                                                  cur2H, nullptr, U, I, M);
    gather_kernel<2><<<gblocks, 256, 0, stream>>>(rowptr, ent, cur2H, cur0H, cur1H,
                                                  nullptr, out, U, I, M);
}

// Round 20
// 237.280 us; speedup vs baseline: 1.1540x; 1.1540x over previous
//
#include <hip/hip_runtime.h>

#define EMB_D 64
#define CSHIFT 9    // class = row >> 9 (512 rows/class)
#define CROWS  (1 << CSHIFT)
#define CMASK  (CROWS - 1)
#define MAXC 384    // max classes (M <= 196608; col fits 18 bits)
#define SFLAG (1 << 27)
#define EPB 4096    // edges per bin/count block (16 per thread)

typedef float    float4v __attribute__((ext_vector_type(4)));
typedef float    float8v __attribute__((ext_vector_type(8)));
typedef _Float16 half4v  __attribute__((ext_vector_type(4)));
typedef _Float16 half8v  __attribute__((ext_vector_type(8)));

__device__ inline float8v tof32x8(half8v v) { return __builtin_convertvector(v, float8v); }

// ---------------------------------------------------------------------------
// class_cnt: per-block per-class entry counts. EPB edges/block, LDS
// histogram -> DENSE row store percls[blk][c] (no global atomics at all).
// ---------------------------------------------------------------------------
__global__ void __launch_bounds__(256) class_cnt(const int* __restrict__ eu,
                                                 const int* __restrict__ ei,
                                                 int E, int nbE,
                                                 const int* __restrict__ sr, int S,
                                                 int U, int* __restrict__ percls) {
    __shared__ int hist[MAXC];
    for (int t = threadIdx.x; t < MAXC; t += 256) hist[t] = 0;
    __syncthreads();
    int blk = blockIdx.x;
    if (blk < nbE) {
        int e0 = blk * EPB, e1 = min(e0 + EPB, E);
        for (int e = e0 + threadIdx.x; e < e1; e += 256) {
            atomicAdd(&hist[eu[e] >> CSHIFT], 1);
            atomicAdd(&hist[(U + ei[e]) >> CSHIFT], 1);
        }
    } else {
        int e0 = (blk - nbE) * EPB, e1 = min(e0 + EPB, S);
        for (int e = e0 + threadIdx.x; e < e1; e += 256) {
            atomicAdd(&hist[(U + sr[e]) >> CSHIFT], 1);
        }
    }
    __syncthreads();
    for (int t = threadIdx.x; t < MAXC; t += 256)
        percls[(long)blk * MAXC + t] = hist[t];
}

// ---------------------------------------------------------------------------
// colscan: one block per class c. Exclusive scan over blocks of
// percls[blk][c] -> per-block chunk base offsets; total -> ctot[c].
// ---------------------------------------------------------------------------
__global__ void __launch_bounds__(512) colscan(int* __restrict__ percls, int NB,
                                               int* __restrict__ ctot) {
    __shared__ int sh[512];
    int c = blockIdx.x;
    int t = threadIdx.x;
    int v = (t < NB) ? percls[(long)t * MAXC + c] : 0;
    sh[t] = v;
    __syncthreads();
    for (int ofs = 1; ofs < 512; ofs <<= 1) {
        int x = (t >= ofs) ? sh[t - ofs] : 0;
        __syncthreads();
        sh[t] += x;
        __syncthreads();
    }
    if (t < NB) percls[(long)t * MAXC + c] = sh[t] - v;  // exclusive
    if (t == 511) ctot[c] = sh[511];
}

// ---------------------------------------------------------------------------
// class_scan: 1-block exclusive scan over NC class totals -> bkptr.
// ---------------------------------------------------------------------------
__global__ void __launch_bounds__(512) class_scan(const int* __restrict__ ctot, int NC,
                                                  int* __restrict__ bkptr) {
    __shared__ int sh[512];
    int t = threadIdx.x;
    int v = (t < NC) ? ctot[t] : 0;
    sh[t] = v;
    __syncthreads();
    for (int ofs = 1; ofs < 512; ofs <<= 1) {
        int x = (t >= ofs) ? sh[t - ofs] : 0;
        __syncthreads();
        sh[t] += x;
        __syncthreads();
    }
    if (t < NC) bkptr[t] = sh[t] - v;
    if (t == 511) bkptr[NC] = sh[511];
}

// ---------------------------------------------------------------------------
// bin: single-pass append into per-class buckets. Chunk base comes from
// bkptr[c] + percls[blk][c] (precomputed, no global atomics); intra-chunk
// offset via LDS hist. ~28-entry contiguous chunks -> ~1.3x write amp.
// Entry .x = (sflag<<27) | (row_lo<<18) | col ; .y = sv bits (s) or 0 (bip).
// ---------------------------------------------------------------------------
__global__ void __launch_bounds__(256) bin_kernel(const int* __restrict__ eu,
                                                  const int* __restrict__ ei,
                                                  int E, int nbE,
                                                  const int* __restrict__ sr,
                                                  const int* __restrict__ sc,
                                                  const float* __restrict__ sv, int S,
                                                  int U,
                                                  const int* __restrict__ bkptr,
                                                  const int* __restrict__ percls,
                                                  int2* __restrict__ bent) {
    __shared__ int hist[MAXC];
    __shared__ int base[MAXC];
    int blk = blockIdx.x;
    for (int t = threadIdx.x; t < MAXC; t += 256) {
        base[t] = bkptr[t] + percls[(long)blk * MAXC + t];
        hist[t] = 0;
    }
    __syncthreads();

    if (blk < nbE) {
        int e0 = blk * EPB, e1 = min(e0 + EPB, E);
        for (int e = e0 + threadIdx.x; e < e1; e += 256) {
            int u  = eu[e];
            int iv = U + ei[e];
            int c0 = u >> CSHIFT, c1 = iv >> CSHIFT;
            int o0 = atomicAdd(&hist[c0], 1);
            bent[base[c0] + o0] = make_int2(((u & CMASK) << 18) | iv, 0);
            int o1 = atomicAdd(&hist[c1], 1);
            bent[base[c1] + o1] = make_int2(((iv & CMASK) << 18) | u, 0);
        }
    } else {
        int e0 = (blk - nbE) * EPB, e1 = min(e0 + EPB, S);
        for (int e = e0 + threadIdx.x; e < e1; e += 256) {
            int dst = U + sr[e];
            int c = dst >> CSHIFT;
            int o = atomicAdd(&hist[c], 1);
            bent[base[c] + o] = make_int2(SFLAG | ((dst & CMASK) << 18) | (U + sc[e]),
                                          __float_as_int(sv[e]));
        }
    }
}

// ---------------------------------------------------------------------------
// cls_hist (pass A): one 1024-thread block per 512-row class. Streams its
// bucket: LDS histograms (bip-degree + total per row) -> norm =
// rsqrt(bipdeg+1), LDS scan -> rowptr. No global row atomics anywhere.
// ---------------------------------------------------------------------------
__global__ void __launch_bounds__(1024) cls_hist(const int* __restrict__ bkptr,
                                                 const int2* __restrict__ bent,
                                                 float* __restrict__ norm,
                                                 int* __restrict__ rowptr, int M) {
    __shared__ int cntb[CROWS];
    __shared__ int cntt[CROWS];
    int c   = blockIdx.x;
    int rlo = c << CSHIFT;
    int nrows = min(CROWS, M - rlo);
    if (threadIdx.x < CROWS) {
        cntb[threadIdx.x] = 0;
        cntt[threadIdx.x] = 0;
    }
    __syncthreads();

    int beg = bkptr[c], end = bkptr[c + 1];
    for (int k = beg + threadIdx.x; k < end; k += 1024) {
        int x = bent[k].x;
        int rl = (x >> 18) & CMASK;
        atomicAdd(&cntt[rl], 1);
        if (!(x & SFLAG)) atomicAdd(&cntb[rl], 1);
    }
    __syncthreads();

    int my = 0;
    if (threadIdx.x < CROWS) {
        my = cntt[threadIdx.x];
        if (threadIdx.x < nrows)
            norm[rlo + threadIdx.x] = rsqrtf((float)cntb[threadIdx.x] + 1.0f);
    }
    for (int ofs = 1; ofs < CROWS; ofs <<= 1) {
        int x = (threadIdx.x >= ofs && threadIdx.x < CROWS) ? cntt[threadIdx.x - ofs] : 0;
        __syncthreads();
        if (threadIdx.x < CROWS) cntt[threadIdx.x] += x;
        __syncthreads();
    }
    if (threadIdx.x < CROWS && threadIdx.x < nrows)
        rowptr[rlo + threadIdx.x] = beg + cntt[threadIdx.x] - my;   // exclusive
    if (threadIdx.x == 0) rowptr[rlo + nrows] = end;  // covers rowptr[M]
}

// ---------------------------------------------------------------------------
// cls_scatter (pass B): one 1024-thread block per class. Row cursors AND
// own-class norms in LDS; re-streams the bucket (L2-hot from pass A) and
// writes final (col, w) entries into the exclusively-owned CSR window
// (single XCD, temporally dense -> ~1x write amp). Bip weight computed as
// norm[row]*norm[col] (same operand order as fill_w -> bit-identical).
// ---------------------------------------------------------------------------
__global__ void __launch_bounds__(1024) cls_scatter(const int* __restrict__ bkptr,
                                                    const int2* __restrict__ bent,
                                                    const float* __restrict__ norm,
                                                    const int* __restrict__ rowptr,
                                                    int2* __restrict__ ent, int M) {
    __shared__ int   cur[CROWS];
    __shared__ float nloc[CROWS];
    int c   = blockIdx.x;
    int rlo = c << CSHIFT;
    int nrows = min(CROWS, M - rlo);
    if (threadIdx.x < CROWS) {
        int r = (threadIdx.x < nrows) ? rlo + threadIdx.x : rlo;
        cur[threadIdx.x]  = rowptr[r];
        nloc[threadIdx.x] = norm[r];
    }
    __syncthreads();

    int beg = bkptr[c], end = bkptr[c + 1];
    for (int k = beg + threadIdx.x; k < end; k += 1024) {
        int2 e = bent[k];
        int rl  = (e.x >> 18) & CMASK;
        int col = e.x & 0x3FFFF;
        int p = atomicAdd(&cur[rl], 1);
        float w = (e.x & SFLAG) ? __int_as_float(e.y) : nloc[rl] * norm[col];
        ent[p] = make_int2(col, __float_as_int(w));
    }
}

// ---------------------------------------------------------------------------
// cur0 (fp16) = concat(user_emb, item_emb)
// ---------------------------------------------------------------------------
__global__ void init_kernel(const float4v* __restrict__ ue, const float4v* __restrict__ ie,
                            long u4, long total4, half4v* __restrict__ curH) {
    long stride = (long)gridDim.x * blockDim.x;
    for (long idx = (long)blockIdx.x * blockDim.x + threadIdx.x; idx < total4; idx += stride) {
        float4v v = (idx < u4) ? ue[idx] : ie[idx - u4];
        curH[idx] = __builtin_convertvector(v, half4v);
    }
}

// ---------------------------------------------------------------------------
// gather: ONE 8-lane group per destination row (8 rows per wave), half8
// 16 B loads, 4-deep masked software pipeline (36 VGPR sweet spot, proven
// rounds 16/18; 8-deep regressed via occupancy cliff) -> 32 outstanding
// row loads per wave. Heavy-first: item rows first.
// MODE 0: curH -> dstH (pure propagate, fp16)
// MODE 2: curH=e2 random-read -> out = 0.25*(e0+e1+e2+acc); e0/e1/e2 are
//         sequential fp16 own-row reads (deferred sum: no fp32 round-trip)
// ---------------------------------------------------------------------------
template <int MODE>
__global__ void __launch_bounds__(256) gather_kernel(const int* __restrict__ rowptr,
                                                     const int2* __restrict__ ent,
                                                     const _Float16* __restrict__ curH,
                                                     const _Float16* __restrict__ cur0H,
                                                     const _Float16* __restrict__ cur1H,
                                                     _Float16* __restrict__ dstH,
                                                     float* __restrict__ out,
                                                     int U, int I, int M) {
    int raw = (int)((((long)blockIdx.x * blockDim.x) + threadIdx.x) >> 3);
    int l   = threadIdx.x & 7;
    if (raw >= M) return;
    int row = (raw < I) ? (U + raw) : (raw - I);   // heavy-first: items first
    int beg = rowptr[row];
    int end = rowptr[row + 1];
    const half8v* curv = (const half8v*)(const void*)curH;

    float8v acc = {0.f, 0.f, 0.f, 0.f, 0.f, 0.f, 0.f, 0.f};
    int j = beg;
    int2 a0 = (j + 0 < end) ? ent[j + 0] : make_int2(0, 0);
    int2 a1 = (j + 1 < end) ? ent[j + 1] : make_int2(0, 0);
    int2 a2 = (j + 2 < end) ? ent[j + 2] : make_int2(0, 0);
    int2 a3 = (j + 3 < end) ? ent[j + 3] : make_int2(0, 0);
    half8v v0 = curv[(long)a0.x * 8 + l];
    half8v v1 = curv[(long)a1.x * 8 + l];
    half8v v2 = curv[(long)a2.x * 8 + l];
    half8v v3 = curv[(long)a3.x * 8 + l];
    while (j + 4 < end) {
        int jn = j + 4;
        int2 b0 = (jn + 0 < end) ? ent[jn + 0] : make_int2(0, 0);
        int2 b1 = (jn + 1 < end) ? ent[jn + 1] : make_int2(0, 0);
        int2 b2 = (jn + 2 < end) ? ent[jn + 2] : make_int2(0, 0);
        int2 b3 = (jn + 3 < end) ? ent[jn + 3] : make_int2(0, 0);
        half8v u0 = curv[(long)b0.x * 8 + l];
        half8v u1 = curv[(long)b1.x * 8 + l];
        half8v u2 = curv[(long)b2.x * 8 + l];
        half8v u3 = curv[(long)b3.x * 8 + l];
        acc += __int_as_float(a0.y) * tof32x8(v0);
        acc += __int_as_float(a1.y) * tof32x8(v1);
        acc += __int_as_float(a2.y) * tof32x8(v2);
        acc += __int_as_float(a3.y) * tof32x8(v3);
        a0 = b0; a1 = b1; a2 = b2; a3 = b3;
        v0 = u0; v1 = u1; v2 = u2; v3 = u3;
        j = jn;
    }
    acc += __int_as_float(a0.y) * tof32x8(v0);
    acc += __int_as_float(a1.y) * tof32x8(v1);
    acc += __int_as_float(a2.y) * tof32x8(v2);
    acc += __int_as_float(a3.y) * tof32x8(v3);

    long o8 = (long)row * 8 + l;
    if (MODE == 0) {
        ((half8v*)dstH)[o8] = __builtin_convertvector(acc, half8v);
    } else {
        float8v e0 = tof32x8(((const half8v*)cur0H)[o8]);
        float8v e1 = tof32x8(((const half8v*)cur1H)[o8]);
        float8v e2 = tof32x8(curv[o8]);
        ((float8v*)out)[o8] = 0.25f * (e0 + e1 + e2 + acc);
    }
}

extern "C" void kernel_launch(void* const* d_in, const int* in_sizes, int n_in,
                              void* d_out, int out_size, void* d_ws, size_t ws_size,
                              hipStream_t stream) {
    const float* user_emb = (const float*)d_in[0];
    const float* item_emb = (const float*)d_in[1];
    const int*   edge_user = (const int*)d_in[2];
    const int*   edge_item = (const int*)d_in[3];
    const int*   s_row = (const int*)d_in[4];
    const int*   s_col = (const int*)d_in[5];
    const float* s_val = (const float*)d_in[6];
    float* out = (float*)d_out;

    const int U = in_sizes[0] / EMB_D;
    const int I = in_sizes[1] / EMB_D;
    const int M = U + I;
    const int E = in_sizes[2];
    const int S = in_sizes[4];
    const long MD = (long)M * EMB_D;
    const long NT = 2L * E + S;             // merged CSR entries
    const int NC = (M + CMASK) >> CSHIFT;   // number of row classes

    const int nbE2 = (E + EPB - 1) / EPB;
    const int nbS2 = (S + EPB - 1) / EPB;
    const int NB = nbE2 + nbS2;             // <= 512 for these sizes

    // workspace carve-up, 16B-aligned chunks
    char* p = (char*)d_ws;
    auto carve = [&](long bytes) {
        char* q = p;
        p += (bytes + 15) & ~15L;
        return q;
    };
    _Float16* cur0H = (_Float16*)carve(MD * sizeof(_Float16));  // e0 (fp16)
    _Float16* cur1H = (_Float16*)carve(MD * sizeof(_Float16));  // e1 (fp16)
    // cur2H (e2, fp16) aliases the bucket array: bucket dead before e2 written
    long aliasBytes = MD * (long)sizeof(_Float16) > (NT + 8) * (long)sizeof(int2)
                        ? MD * (long)sizeof(_Float16) : (NT + 8) * (long)sizeof(int2);
    char* aliasRgn = carve(aliasBytes);
    _Float16* cur2H = (_Float16*)aliasRgn;
    int2*     bent  = (int2*)aliasRgn;
    float* norm   = (float*)carve((long)M * sizeof(float));
    int*   rowptr = (int*)carve((long)(M + 1) * sizeof(int));
    int*   percls = (int*)carve((long)NB * MAXC * sizeof(int));
    int*   ctot   = (int*)carve((long)MAXC * sizeof(int));
    int*   bkptr  = (int*)carve((long)(MAXC + 1) * sizeof(int));
    int2*  ent    = (int2*)carve((NT + 8) * sizeof(int2));

    // 1) per-block per-class counts (dense stores, zero global atomics)
    class_cnt<<<NB, 256, 0, stream>>>(edge_user, edge_item, E, nbE2,
                                      s_row, S, U, percls);

    // 2) column scan over blocks -> chunk bases; class scan -> bkptr
    colscan<<<NC, 512, 0, stream>>>(percls, NB, ctot);
    class_scan<<<1, 512, 0, stream>>>(ctot, NC, bkptr);

    // 3) single-pass bin into class buckets (precomputed chunk bases)
    bin_kernel<<<NB, 256, 0, stream>>>(edge_user, edge_item, E, nbE2,
                                       s_row, s_col, s_val, S,
                                       U, bkptr, percls, bent);

    // 4a) pass A: per-class histograms -> norm + rowptr
    cls_hist<<<NC, 1024, 0, stream>>>(bkptr, bent, norm, rowptr, M);

    // 4b) pass B: scatter with in-flight weight computation
    cls_scatter<<<NC, 1024, 0, stream>>>(bkptr, bent, norm, rowptr, ent, M);

    // 5) init cur0 (fp16)
    init_kernel<<<2048, 256, 0, stream>>>((const float4v*)user_emb, (const float4v*)item_emb,
                                          (long)U * (EMB_D / 4), MD / 4, (half4v*)cur0H);

    // 6) L=3 gather layers: two pure propagates + deferred final sum
    const int gblocks = (int)(((long)M * 8 + 255) / 256);
    gather_kernel<0><<<gblocks, 256, 0, stream>>>(rowptr, ent, cur0H, nullptr, nullptr,
                                                  cur1H, nullptr, U, I, M);
    gather_kernel<0><<<gblocks, 256, 0, stream>>>(rowptr, ent, cur1H, nullptr, nullptr,
                                                  cur2H, nullptr, U, I, M);
    gather_kernel<2><<<gblocks, 256, 0, stream>>>(rowptr, ent, cur2H, cur0H, cur1H,
                                                  nullptr, out, U, I, M);
}